// Round 3
// baseline (131.135 us; speedup 1.0000x reference)
//
#include <hip/hip_runtime.h>

#define NB    256   // neighbors
#define DIN   64
#define LATD  128
#define ECD   32

typedef __attribute__((ext_vector_type(8))) __bf16 bf16x8;
typedef __attribute__((ext_vector_type(4))) float f32x4;

#define XS_STRIDE 72   // ws row stride for WcT/WfT (bf16 elems)
#define EC_STRIDE 40   // 32 data + 8 pad (LDS bank spread)
#define WA_STRIDE 40

// d_ws layout (unsigned short elements)
#define WS_WC 0                     // WcT  [32][72]
#define WS_WF (32 * 72)             // WfT  [128][72]
#define WS_WA (32 * 72 + 128 * 72)  // WaTm [128][40]  (Wa rows 32..63, transposed, *log2e)

#define MFMA(a, b, c) __builtin_amdgcn_mfma_f32_16x16x32_bf16((a), (b), (c), 0, 0, 0)

__device__ __forceinline__ unsigned short f2bf(float f) {
    unsigned u = __builtin_bit_cast(unsigned, f);
    u += 0x7fffu + ((u >> 16) & 1u);   // round-to-nearest-even
    return (unsigned short)(u >> 16);
}

// Packed f32->bf16 RNE: 1 instruction per 2 elements (gfx950; no builtin).
__device__ __forceinline__ unsigned cvt2(float lo, float hi) {
    unsigned r;
    asm("v_cvt_pk_bf16_f32 %0, %1, %2" : "=v"(r) : "v"(lo), "v"(hi));
    return r;
}

__device__ __forceinline__ bf16x8 pack8(float4 a, float4 b) {
    union { unsigned u[4]; bf16x8 v; } r;
    r.u[0] = cvt2(a.x, a.y);
    r.u[1] = cvt2(a.z, a.w);
    r.u[2] = cvt2(b.x, b.y);
    r.u[3] = cvt2(b.z, b.w);
    return r.v;
}

// Pre-transpose weights into bf16 B-fragment-friendly [n][k] layouts in d_ws.
// Wa rows 32..63 are pre-scaled by log2e so the kernel can use exp2 directly.
__global__ __launch_bounds__(256) void prep_kernel(
    const float* __restrict__ Wc, const float* __restrict__ Wf,
    const float* __restrict__ Wa, unsigned short* __restrict__ ws)
{
    int t = blockIdx.x * blockDim.x + threadIdx.x;
    int stride = gridDim.x * blockDim.x;
    for (int i = t; i < 32 * 64; i += stride) {
        int n = i >> 6, k = i & 63;
        ws[WS_WC + n * XS_STRIDE + k] = f2bf(Wc[k * ECD + n]);
    }
    for (int i = t; i < 128 * 64; i += stride) {
        int n = i >> 6, k = i & 63;
        ws[WS_WF + n * XS_STRIDE + k] = f2bf(Wf[k * LATD + n]);
    }
    for (int i = t; i < 128 * 32; i += stride) {
        int n = i >> 5, k = i & 31;
        ws[WS_WA + n * WA_STRIDE + k] = f2bf(Wa[(ECD + k) * LATD + n] * 1.44269504f);
    }
}

// One block per batch element, 512 threads = 8 waves, each wave owns 32
// neighbor rows (2 m-tiles).
// This revision combines the two proven halves: r1 proved 8-wave/64-VGPR
// occupancy is reachable (compiled at 32 VGPR) and costs only ~12% even
// with crippled loop bodies; r2 proved the register-disciplined loop body
// (ec frags in regs, depth-1 weight prefetch, bias folded into MFMA C,
// Wa pre-scaled). Here: both at once -> 8 waves/SIMD with r2-quality
// per-wave chains. Est. ~55 VGPR < 64 cap.
// Key algebra (verified): self_rep/mean_rep/ba constant along n -> cancel
// in softmax(axis=n); att = softmax_n(enc_comm @ Wa[32:64]); local_data /
// Wa[0:32] / Wa[64:96] / ba never touch the output.
__global__ __launch_bounds__(512, 8) void arm_main(
    const float* __restrict__ xg,   // neighbor [B][256][64]
    const float* __restrict__ bcv,  // bc [32]
    const float* __restrict__ bfv,  // bf [128]
    const float* __restrict__ wl,   // Wl [128][128]
    const float* __restrict__ blv,  // bl [128]
    const unsigned short* __restrict__ ws,
    float* __restrict__ out)        // [B][128]
{
    __shared__ unsigned short ecs[NB * EC_STRIDE];  // 20480 B, bf16 enc_comm
    __shared__ float aggnum[8][LATD];
    __shared__ float aggden[8][LATD];
    __shared__ float aggfull[LATD];
    __shared__ float wlpart[4][LATD];

    const int b    = blockIdx.x;
    const int tid  = threadIdx.x;
    const int lane = tid & 63;
    const int w    = tid >> 6;   // wave id 0..7, owns rows 32w..32w+31
    const int l15  = lane & 15;
    const int q    = lane >> 4;

    // ---- load X[b] rows directly into A-fragments (global -> reg, cvt bf16) ----
    // A-frag: row = lane&15 (within tile), k = quad*8 + j  -> 8 contiguous floats.
    const float* xb = xg + (size_t)b * NB * DIN;
    bf16x8 xfrag[2][2];
    #pragma unroll
    for (int t = 0; t < 2; ++t) {
        const float* p = xb + (w * 32 + t * 16 + l15) * DIN + q * 8;
        float4 s0 = *reinterpret_cast<const float4*>(p);
        float4 s1 = *reinterpret_cast<const float4*>(p + 4);
        float4 s2 = *reinterpret_cast<const float4*>(p + 32);
        float4 s3 = *reinterpret_cast<const float4*>(p + 36);
        xfrag[t][0] = pack8(s0, s1);
        xfrag[t][1] = pack8(s2, s3);
    }

    // ---- enc_comm = relu(X*Wc + bc) -> ecs bf16 (same-wave rows only) ----
    {
        bf16x8 wfrag[2][2];   // [khalf][colblock]
        #pragma unroll
        for (int ks = 0; ks < 2; ++ks)
            #pragma unroll
            for (int nb = 0; nb < 2; ++nb)
                wfrag[ks][nb] = *reinterpret_cast<const bf16x8*>(
                    &ws[WS_WC + (nb * 16 + l15) * XS_STRIDE + ks * 32 + q * 8]);

        float bc0 = bcv[l15], bc1 = bcv[16 + l15];
        #pragma unroll
        for (int t = 0; t < 2; ++t) {
            int rowA = w * 32 + t * 16;
            // bias folded into accumulator init (C/D col = lane&15 -> bias
            // uniform across the 4 result regs).
            f32x4 a0 = {bc0, bc0, bc0, bc0};
            f32x4 a1 = {bc1, bc1, bc1, bc1};
            #pragma unroll
            for (int ks = 0; ks < 2; ++ks) {
                a0 = MFMA(xfrag[t][ks], wfrag[ks][0], a0);
                a1 = MFMA(xfrag[t][ks], wfrag[ks][1], a1);
            }
            #pragma unroll
            for (int r = 0; r < 4; ++r) {
                int row = rowA + q * 4 + r;   // C/D: row = quad*4 + reg
                unsigned pk = cvt2(fmaxf(a0[r], 0.f), fmaxf(a1[r], 0.f));
                ecs[row * EC_STRIDE + l15]      = (unsigned short)pk;
                ecs[row * EC_STRIDE + 16 + l15] = (unsigned short)(pk >> 16);
            }
        }
    }

    // ---- ec A-fragments held in REGISTERS across the whole g-loop (r1's
    // mistake was re-reading these from LDS 16x inside the loop) ----
    bf16x8 ecfrag[2];
    #pragma unroll
    for (int t = 0; t < 2; ++t)
        ecfrag[t] = *reinterpret_cast<const bf16x8*>(
            &ecs[(w * 32 + t * 16 + l15) * EC_STRIDE + q * 8]);

    // ---- fused g-loop: enc_feature + logits + unnormalized softmax agg ----
    // No max-subtraction (logits are O(+-3); exp2 safe), no barriers; each
    // wave emits num/den partials over its 32 n-rows. Weights for g+1 are
    // software-prefetched; num/den split per-t to shorten serial FMA chains.
    const unsigned short* wfb = ws + WS_WF;
    const unsigned short* wab = ws + WS_WA;

    bf16x8 wf0 = *reinterpret_cast<const bf16x8*>(&wfb[l15 * XS_STRIDE + q * 8]);
    bf16x8 wf1 = *reinterpret_cast<const bf16x8*>(&wfb[l15 * XS_STRIDE + 32 + q * 8]);
    bf16x8 wag = *reinterpret_cast<const bf16x8*>(&wab[l15 * WA_STRIDE + q * 8]);
    float  bfl = bfv[l15];

    for (int g = 0; g < 8; ++g) {
        bf16x8 nwf0, nwf1, nwag;
        float  nbfl = 0.f;
        if (g < 7) {
            int r0 = (g + 1) * 16 + l15;
            nwf0 = *reinterpret_cast<const bf16x8*>(&wfb[r0 * XS_STRIDE + q * 8]);
            nwf1 = *reinterpret_cast<const bf16x8*>(&wfb[r0 * XS_STRIDE + 32 + q * 8]);
            nwag = *reinterpret_cast<const bf16x8*>(&wab[r0 * WA_STRIDE + q * 8]);
            nbfl = bfv[r0];
        }

        // bf bias folded into accumulator init; logits keep C=0 (ba cancels).
        f32x4 z0 = {bfl, bfl, bfl, bfl};
        z0 = MFMA(xfrag[0][0], wf0, z0);
        f32x4 ef0 = MFMA(xfrag[0][1], wf1, z0);
        f32x4 z1 = {bfl, bfl, bfl, bfl};
        z1 = MFMA(xfrag[1][0], wf0, z1);
        f32x4 ef1 = MFMA(xfrag[1][1], wf1, z1);
        f32x4 zz = {0.f, 0.f, 0.f, 0.f};
        f32x4 lg0 = MFMA(ecfrag[0], wag, zz);
        f32x4 lg1 = MFMA(ecfrag[1], wag, zz);

        float num0 = 0.f, den0 = 0.f, num1 = 0.f, den1 = 0.f;
        #pragma unroll
        for (int r = 0; r < 4; ++r) {
            float e0 = fmaxf(ef0[r], 0.f);
            float p0 = exp2f(lg0[r]);      // Wa pre-scaled by log2e in prep
            num0 = fmaf(p0, e0, num0);
            den0 += p0;
            float e1 = fmaxf(ef1[r], 0.f);
            float p1 = exp2f(lg1[r]);
            num1 = fmaf(p1, e1, num1);
            den1 += p1;
        }
        float num = num0 + num1, den = den0 + den1;
        num += __shfl_xor(num, 16, 64); num += __shfl_xor(num, 32, 64);
        den += __shfl_xor(den, 16, 64); den += __shfl_xor(den, 32, 64);
        if (lane < 16) {
            aggnum[w][g * 16 + lane] = num;
            aggden[w][g * 16 + lane] = den;
        }

        if (g < 7) { wf0 = nwf0; wf1 = nwf1; wag = nwag; bfl = nbfl; }
    }
    __syncthreads();

    // ---- combine wave partials: aggregated[k] = sum(num)/sum(den) ----
    if (tid < 128) {
        float num = 0.f, den = 0.f;
        #pragma unroll
        for (int i = 0; i < 8; ++i) {
            num += aggnum[i][tid];
            den += aggden[i][tid];
        }
        aggfull[tid] = num / den;
    }
    __syncthreads();

    // ---- out = relu(agg @ Wl + bl), k-range split over thread quarters ----
    {
        int c = tid & 127, h = tid >> 7;   // h in 0..3, 32 k each
        float acc = 0.f;
        #pragma unroll 8
        for (int k = h * 32; k < h * 32 + 32; ++k)
            acc += aggfull[k] * wl[k * LATD + c];
        wlpart[h][c] = acc;
    }
    __syncthreads();
    if (tid < 128)
        out[(size_t)b * LATD + tid] =
            fmaxf(wlpart[0][tid] + wlpart[1][tid] + wlpart[2][tid] +
                      wlpart[3][tid] + blv[tid], 0.f);
}

extern "C" void kernel_launch(void* const* d_in, const int* in_sizes, int n_in,
                              void* d_out, int out_size, void* d_ws, size_t ws_size,
                              hipStream_t stream)
{
    const float* xg  = (const float*)d_in[1];
    const float* bc_ = (const float*)d_in[3];
    const float* wc  = (const float*)d_in[2];
    const float* bf_ = (const float*)d_in[5];
    const float* wf  = (const float*)d_in[4];
    const float* wa  = (const float*)d_in[6];
    const float* wl  = (const float*)d_in[8];
    const float* bl_ = (const float*)d_in[9];
    unsigned short* wsp = (unsigned short*)d_ws;   // needs 33,280 B of ws
    float* out = (float*)d_out;

    prep_kernel<<<8, 256, 0, stream>>>(wc, wf, wa, wsp);
    arm_main<<<1024, 512, 0, stream>>>(xg, bc_, bf_, wl, bl_, wsp, out);
}

// Round 5
// 125.503 us; speedup vs baseline: 1.0449x; 1.0449x over previous
//
#include <hip/hip_runtime.h>

#define NB    256   // neighbors
#define DIN   64
#define LATD  128
#define ECD   32

typedef __attribute__((ext_vector_type(8))) __bf16 bf16x8;
typedef __attribute__((ext_vector_type(4))) float f32x4;

#define XS_STRIDE 72   // ws row stride for WcT/WfT (bf16 elems)
#define EC_STRIDE 40   // 32 data + 8 pad (LDS bank spread)
#define WA_STRIDE 40

// d_ws layout (unsigned short elements)
#define WS_WC 0                     // WcT  [32][72]
#define WS_WF (32 * 72)             // WfT  [128][72]
#define WS_WA (32 * 72 + 128 * 72)  // WaTm [128][40]  (Wa rows 32..63, transposed, *log2e)

#define MFMA(a, b, c) __builtin_amdgcn_mfma_f32_16x16x32_bf16((a), (b), (c), 0, 0, 0)

__device__ __forceinline__ unsigned short f2bf(float f) {
    unsigned u = __builtin_bit_cast(unsigned, f);
    u += 0x7fffu + ((u >> 16) & 1u);   // round-to-nearest-even
    return (unsigned short)(u >> 16);
}

// Packed f32->bf16 RNE: 1 instruction per 2 elements (gfx950; no builtin).
// Plain VALU op -> no TRANS hazard, safe as opaque asm (verified r2/r3).
__device__ __forceinline__ unsigned cvt2(float lo, float hi) {
    unsigned r;
    asm("v_cvt_pk_bf16_f32 %0, %1, %2" : "=v"(r) : "v"(lo), "v"(hi));
    return r;
}

// Single-instruction exp2. r4 LESSON: raw `asm("v_exp_f32")` FAILS —
// TRANS-op results need a wait state before a dependent VALU read, and the
// compiler's hazard recognizer can't see through opaque asm -> consumer
// read stale data (absmax 1.5). The builtin emits the same v_exp_f32 but
// with compiler-managed hazard handling. Fallback embeds the s_nop.
#if __has_builtin(__builtin_amdgcn_exp2f)
__device__ __forceinline__ float fexp2(float x) {
    return __builtin_amdgcn_exp2f(x);
}
#else
__device__ __forceinline__ float fexp2(float x) {
    float r;
    asm("v_exp_f32 %0, %1\n\ts_nop 1" : "=v"(r) : "v"(x));
    return r;
}
#endif

__device__ __forceinline__ bf16x8 pack8(float4 a, float4 b) {
    union { unsigned u[4]; bf16x8 v; } r;
    r.u[0] = cvt2(a.x, a.y);
    r.u[1] = cvt2(a.z, a.w);
    r.u[2] = cvt2(b.x, b.y);
    r.u[3] = cvt2(b.z, b.w);
    return r.v;
}

// Pre-transpose weights into bf16 B-fragment-friendly [n][k] layouts in d_ws.
// Wa rows 32..63 are pre-scaled by log2e so the kernel can use exp2 directly.
__global__ __launch_bounds__(256) void prep_kernel(
    const float* __restrict__ Wc, const float* __restrict__ Wf,
    const float* __restrict__ Wa, unsigned short* __restrict__ ws)
{
    int t = blockIdx.x * blockDim.x + threadIdx.x;
    int stride = gridDim.x * blockDim.x;
    for (int i = t; i < 32 * 64; i += stride) {
        int n = i >> 6, k = i & 63;
        ws[WS_WC + n * XS_STRIDE + k] = f2bf(Wc[k * ECD + n]);
    }
    for (int i = t; i < 128 * 64; i += stride) {
        int n = i >> 6, k = i & 63;
        ws[WS_WF + n * XS_STRIDE + k] = f2bf(Wf[k * LATD + n]);
    }
    for (int i = t; i < 128 * 32; i += stride) {
        int n = i >> 5, k = i & 31;
        ws[WS_WA + n * WA_STRIDE + k] = f2bf(Wa[(ECD + k) * LATD + n] * 1.44269504f);
    }
}

// One block per batch element, 256 threads = 4 waves, each wave owns 64
// neighbor rows (4 m-tiles). Ladder: r2 (this config, exp2f) ~36 us best;
// r1 (8w, LDS-heavy) 43; r3 (8w, reg-quality) 39 -> tile-ILP beats wave
// count; occupancy is NOT the constraint. This rev = r2 + single-inst exp2
// (via builtin, r4's asm version had the TRANS hazard) + front-loaded
// small loads (weights/biases issued before the X burst so their latency
// hides under the HBM wait).
// Key algebra (verified): self_rep/mean_rep/ba constant along n -> cancel
// in softmax(axis=n); att = softmax_n(enc_comm @ Wa[32:64]); local_data /
// Wa[0:32] / Wa[64:96] / ba never touch the output.
__global__ __launch_bounds__(256, 4) void arm_main(
    const float* __restrict__ xg,   // neighbor [B][256][64]
    const float* __restrict__ bcv,  // bc [32]
    const float* __restrict__ bfv,  // bf [128]
    const float* __restrict__ wl,   // Wl [128][128]
    const float* __restrict__ blv,  // bl [128]
    const unsigned short* __restrict__ ws,
    float* __restrict__ out)        // [B][128]
{
    __shared__ unsigned short ecs[NB * EC_STRIDE];  // 20480 B, bf16 enc_comm
    __shared__ float aggnum[4][LATD];
    __shared__ float aggden[4][LATD];
    __shared__ float aggfull[LATD];
    __shared__ float wlpart[2][LATD];

    const int b    = blockIdx.x;
    const int tid  = threadIdx.x;
    const int lane = tid & 63;
    const int w    = tid >> 6;   // wave id, owns rows 64w..64w+63 (4 m-tiles)
    const int l15  = lane & 15;
    const int q    = lane >> 4;

    const unsigned short* wfb = ws + WS_WF;
    const unsigned short* wab = ws + WS_WA;

    // ---- front-loaded small loads (L2): Wc frags, g0 weights, biases ----
    // Issued BEFORE the X burst so their ~200-400cy latency hides under the
    // mandatory HBM wait instead of stalling serially after it.
    bf16x8 wfrag[2][2];   // [khalf][colblock]
    #pragma unroll
    for (int ks = 0; ks < 2; ++ks)
        #pragma unroll
        for (int nb = 0; nb < 2; ++nb)
            wfrag[ks][nb] = *reinterpret_cast<const bf16x8*>(
                &ws[WS_WC + (nb * 16 + l15) * XS_STRIDE + ks * 32 + q * 8]);
    bf16x8 wf0 = *reinterpret_cast<const bf16x8*>(&wfb[l15 * XS_STRIDE + q * 8]);
    bf16x8 wf1 = *reinterpret_cast<const bf16x8*>(&wfb[l15 * XS_STRIDE + 32 + q * 8]);
    bf16x8 wag = *reinterpret_cast<const bf16x8*>(&wab[l15 * WA_STRIDE + q * 8]);
    float bc0 = bcv[l15], bc1 = bcv[16 + l15];
    float bfl = bfv[l15];

    // ---- load X[b] rows directly into A-fragments (global -> reg, cvt bf16) ----
    // A-frag: row = lane&15 (within tile), k = quad*8 + j  -> 8 contiguous floats.
    const float* xb = xg + (size_t)b * NB * DIN;
    float4 st[4][4];
    #pragma unroll
    for (int t = 0; t < 4; ++t) {
        const float* p = xb + (w * 64 + t * 16 + l15) * DIN + q * 8;
        st[t][0] = *reinterpret_cast<const float4*>(p);
        st[t][1] = *reinterpret_cast<const float4*>(p + 4);
        st[t][2] = *reinterpret_cast<const float4*>(p + 32);
        st[t][3] = *reinterpret_cast<const float4*>(p + 36);
    }
    bf16x8 xfrag[4][2];
    #pragma unroll
    for (int t = 0; t < 4; ++t) {
        xfrag[t][0] = pack8(st[t][0], st[t][1]);
        xfrag[t][1] = pack8(st[t][2], st[t][3]);
    }

    // ---- enc_comm = relu(X*Wc + bc) -> ecs bf16 (same-wave rows only) ----
    #pragma unroll
    for (int t = 0; t < 4; ++t) {
        int rowA = w * 64 + t * 16;
        // bias folded into accumulator init (C/D col = lane&15 -> bias
        // uniform across the 4 result regs).
        f32x4 a0 = {bc0, bc0, bc0, bc0};
        f32x4 a1 = {bc1, bc1, bc1, bc1};
        #pragma unroll
        for (int ks = 0; ks < 2; ++ks) {
            a0 = MFMA(xfrag[t][ks], wfrag[ks][0], a0);
            a1 = MFMA(xfrag[t][ks], wfrag[ks][1], a1);
        }
        #pragma unroll
        for (int r = 0; r < 4; ++r) {
            int row = rowA + q * 4 + r;   // C/D: row = quad*4 + reg
            unsigned pk = cvt2(fmaxf(a0[r], 0.f), fmaxf(a1[r], 0.f));
            ecs[row * EC_STRIDE + l15]      = (unsigned short)pk;
            ecs[row * EC_STRIDE + 16 + l15] = (unsigned short)(pk >> 16);
        }
    }

    // ---- ec A-fragments held in registers across the whole g-loop ----
    bf16x8 ecfrag[4];
    #pragma unroll
    for (int t = 0; t < 4; ++t)
        ecfrag[t] = *reinterpret_cast<const bf16x8*>(
            &ecs[(w * 64 + t * 16 + l15) * EC_STRIDE + q * 8]);

    // ---- fused g-loop: enc_feature + logits + unnormalized softmax agg ----
    // No max-subtraction (logits are O(+-3); exp2 safe), no barriers; each
    // wave emits num/den partials over its 64 n-rows. Weights for g+1
    // software-prefetched (g0's were loaded at kernel top).
    for (int g = 0; g < 8; ++g) {
        bf16x8 nwf0, nwf1, nwag;
        float  nbfl = 0.f;
        if (g < 7) {
            int r0 = (g + 1) * 16 + l15;
            nwf0 = *reinterpret_cast<const bf16x8*>(&wfb[r0 * XS_STRIDE + q * 8]);
            nwf1 = *reinterpret_cast<const bf16x8*>(&wfb[r0 * XS_STRIDE + 32 + q * 8]);
            nwag = *reinterpret_cast<const bf16x8*>(&wab[r0 * WA_STRIDE + q * 8]);
            nbfl = bfv[r0];
        }

        float num = 0.f, den = 0.f;
        #pragma unroll
        for (int t = 0; t < 4; ++t) {
            // bf bias folded into accumulator init; logits keep C=0 (ba cancels).
            f32x4 z = {bfl, bfl, bfl, bfl};
            z = MFMA(xfrag[t][0], wf0, z);
            f32x4 ef = MFMA(xfrag[t][1], wf1, z);
            f32x4 z2 = {0.f, 0.f, 0.f, 0.f};
            f32x4 lg = MFMA(ecfrag[t], wag, z2);
            #pragma unroll
            for (int r = 0; r < 4; ++r) {
                float e = fmaxf(ef[r], 0.f);
                float p = fexp2(lg[r]);      // Wa pre-scaled by log2e in prep
                num = fmaf(p, e, num);
                den += p;
            }
        }
        num += __shfl_xor(num, 16, 64); num += __shfl_xor(num, 32, 64);
        den += __shfl_xor(den, 16, 64); den += __shfl_xor(den, 32, 64);
        if (lane < 16) {
            aggnum[w][g * 16 + lane] = num;
            aggden[w][g * 16 + lane] = den;
        }

        if (g < 7) { wf0 = nwf0; wf1 = nwf1; wag = nwag; bfl = nbfl; }
    }
    __syncthreads();

    // ---- combine wave partials: aggregated[k] = sum(num)/sum(den) ----
    if (tid < 128) {
        float num = aggnum[0][tid] + aggnum[1][tid] + aggnum[2][tid] + aggnum[3][tid];
        float den = aggden[0][tid] + aggden[1][tid] + aggden[2][tid] + aggden[3][tid];
        aggfull[tid] = num / den;
    }
    __syncthreads();

    // ---- out = relu(agg @ Wl + bl), k-range split over thread halves ----
    {
        int c = tid & 127, h = tid >> 7;
        float acc = 0.f;
        #pragma unroll 16
        for (int k = h * 64; k < h * 64 + 64; ++k)
            acc += aggfull[k] * wl[k * LATD + c];
        wlpart[h][c] = acc;
    }
    __syncthreads();
    if (tid < 128)
        out[(size_t)b * LATD + tid] =
            fmaxf(wlpart[0][tid] + wlpart[1][tid] + blv[tid], 0.f);
}

extern "C" void kernel_launch(void* const* d_in, const int* in_sizes, int n_in,
                              void* d_out, int out_size, void* d_ws, size_t ws_size,
                              hipStream_t stream)
{
    const float* xg  = (const float*)d_in[1];
    const float* wc  = (const float*)d_in[2];
    const float* bc_ = (const float*)d_in[3];
    const float* wf  = (const float*)d_in[4];
    const float* bf_ = (const float*)d_in[5];
    const float* wa  = (const float*)d_in[6];
    const float* wl  = (const float*)d_in[8];
    const float* bl_ = (const float*)d_in[9];
    unsigned short* wsp = (unsigned short*)d_ws;   // needs 33,280 B of ws
    float* out = (float*)d_out;

    prep_kernel<<<8, 256, 0, stream>>>(wc, wf, wa, wsp);
    arm_main<<<1024, 256, 0, stream>>>(xg, bc_, bf_, wl, bl_, wsp, out);
}